// Round 1
// baseline (958.156 us; speedup 1.0000x reference)
//
#include <hip/hip_runtime.h>
#include <hip/hip_bf16.h>

// Problem constants (from setup_inputs): B=4, S=2048, D_IN=2048, D_OUT=2048
constexpr int D_IN  = 2048;
constexpr int D_OUT = 2048;
constexpr int GM = 4 * 2048;      // B*S rows
constexpr int GK = 2 * D_IN;      // 4096 (concat real|imag)
constexpr int GN = 2 * D_OUT;     // 4096 (concat y_real|y_imag channels)

typedef __attribute__((ext_vector_type(8))) short bf16x8;
typedef __attribute__((ext_vector_type(4))) float f32x4;

__device__ inline float quant4(float w) {
    if (w >  0.75f) return  1.0f;
    if (w >  0.25f) return  0.5f;
    if (w < -0.75f) return -1.0f;
    if (w < -0.25f) return -0.5f;
    return 0.0f;
}

__device__ inline unsigned short bf16b(float x) {
    __hip_bfloat16 h = __float2bfloat16(x);
    unsigned short u;
    __builtin_memcpy(&u, &h, 2);
    return u;
}

// ---------------------------------------------------------------------------
// Kernel 1: quantize weights into W_cat (bf16, GN x GK, row-major) and reduce
// sum(|w_re|), sum(|w_im|) into sums[0], sums[1].
// W_cat row n<2048:  [ qre[n,:] | -qim[n,:] ]   -> y_real channels
// W_cat row n>=2048: [ qim[n,:] |  qre[n,:] ]   -> y_imag channels
// ---------------------------------------------------------------------------
__global__ __launch_bounds__(256) void quant_kernel(
        const float* __restrict__ wre, const float* __restrict__ wim,
        unsigned short* __restrict__ wq, float* __restrict__ sums) {
    int idx = blockIdx.x * 256 + threadIdx.x;     // 0 .. D_OUT*D_IN-1
    int o = idx >> 11;                            // /2048
    int k = idx & (D_IN - 1);
    float re = wre[idx], im = wim[idx];
    float qre = quant4(re), qim = quant4(im);
    wq[(size_t)o * GK + k]                       = bf16b(qre);
    wq[(size_t)o * GK + D_IN + k]                = bf16b(-qim);
    wq[(size_t)(D_OUT + o) * GK + k]             = bf16b(qim);
    wq[(size_t)(D_OUT + o) * GK + D_IN + k]      = bf16b(qre);

    float a = fabsf(re), b = fabsf(im);
    for (int off = 32; off; off >>= 1) {
        a += __shfl_down(a, off, 64);
        b += __shfl_down(b, off, 64);
    }
    __shared__ float sa[4], sb[4];
    int lane = threadIdx.x & 63, wv = threadIdx.x >> 6;
    if (lane == 0) { sa[wv] = a; sb[wv] = b; }
    __syncthreads();
    if (threadIdx.x == 0) {
        atomicAdd(&sums[0], sa[0] + sa[1] + sa[2] + sa[3]);
        atomicAdd(&sums[1], sb[0] + sb[1] + sb[2] + sb[3]);
    }
}

// ---------------------------------------------------------------------------
// Kernel 2: LayerNorm over concat row [x_real[m,:], x_imag[m,:]] (4096 elems),
// writes bf16 activations A (GM x GK row-major). One 256-thread block per row.
// ---------------------------------------------------------------------------
__global__ __launch_bounds__(256) void ln_kernel(
        const float* __restrict__ xr, const float* __restrict__ xi,
        const float* __restrict__ gamma, const float* __restrict__ beta,
        unsigned short* __restrict__ A) {
    int m = blockIdx.x;
    int t = threadIdx.x;
    const float4* r4 = (const float4*)(xr + (size_t)m * D_IN);
    const float4* i4 = (const float4*)(xi + (size_t)m * D_IN);
    float4 vr[2], vi[2];
    float s = 0.f, ss = 0.f;
    for (int c = 0; c < 2; c++) {
        float4 v = r4[t + c * 256];
        vr[c] = v;
        s  += v.x + v.y + v.z + v.w;
        ss += v.x * v.x + v.y * v.y + v.z * v.z + v.w * v.w;
        v = i4[t + c * 256];
        vi[c] = v;
        s  += v.x + v.y + v.z + v.w;
        ss += v.x * v.x + v.y * v.y + v.z * v.z + v.w * v.w;
    }
    for (int off = 32; off; off >>= 1) {
        s  += __shfl_down(s, off, 64);
        ss += __shfl_down(ss, off, 64);
    }
    __shared__ float red[8];
    __shared__ float smu, srs;
    int lane = t & 63, wv = t >> 6;
    if (lane == 0) { red[wv] = s; red[4 + wv] = ss; }
    __syncthreads();
    if (t == 0) {
        float S  = red[0] + red[1] + red[2] + red[3];
        float SS = red[4] + red[5] + red[6] + red[7];
        float mu  = S * (1.0f / 4096.0f);
        float var = SS * (1.0f / 4096.0f) - mu * mu;
        smu = mu;
        srs = rsqrtf(var + 1e-6f);
    }
    __syncthreads();
    float mu = smu, rs = srs;
    const float4* g4 = (const float4*)gamma;
    const float4* b4 = (const float4*)beta;
    ushort4* Arow = (ushort4*)(A + (size_t)m * GK);
    for (int c = 0; c < 2; c++) {
        int k4 = t + c * 256;                 // float4 index in real half
        float4 g = g4[k4], b = b4[k4];
        float4 v = vr[c];
        ushort4 o;
        o.x = bf16b((v.x - mu) * rs * g.x + b.x);
        o.y = bf16b((v.y - mu) * rs * g.y + b.y);
        o.z = bf16b((v.z - mu) * rs * g.z + b.z);
        o.w = bf16b((v.w - mu) * rs * g.w + b.w);
        Arow[k4] = o;
        g = g4[512 + k4]; b = b4[512 + k4];
        v = vi[c];
        o.x = bf16b((v.x - mu) * rs * g.x + b.x);
        o.y = bf16b((v.y - mu) * rs * g.y + b.y);
        o.z = bf16b((v.z - mu) * rs * g.z + b.z);
        o.w = bf16b((v.w - mu) * rs * g.w + b.w);
        Arow[512 + k4] = o;
    }
}

// ---------------------------------------------------------------------------
// Kernel 3: GEMM  Y(GM x GN) = A(GM x GK) * W_cat^T, W_cat stored N x K.
// 128x128 tile, BK=64, bf16 16x16x32 MFMA, global_load_lds width-16 staging.
// Epilogue scales by s_re / s_im and writes the y_real / y_imag halves.
// ---------------------------------------------------------------------------
__global__ __launch_bounds__(256, 2) void gemm_kernel(
        const unsigned short* __restrict__ A,
        const unsigned short* __restrict__ Wq,
        const float* __restrict__ sums,
        float* __restrict__ out) {
    constexpr int BM = 128, BN = 128, BK = 64;
    __shared__ unsigned short lsA[BM * BK];
    __shared__ unsigned short lsB[BN * BK];
    int n0 = blockIdx.x * BN;
    int m0 = blockIdx.y * BM;
    int t = threadIdx.x, lane = t & 63, wave = t >> 6;
    int wm = (wave >> 1) * 64;     // wave's m offset within tile
    int wn = (wave & 1) * 64;      // wave's n offset within tile
    int quad = lane >> 4, r = lane & 15;
    int srow = lane >> 3;          // staging: row within 8-row group
    int scol = (lane & 7) * 8;     // staging: bf16 col (8 bf16 = 16B)

    f32x4 acc[4][4] = {};

    for (int k0 = 0; k0 < GK; k0 += BK) {
        // stage A tile (128 rows x 64 cols bf16): 4 issues of 16B per thread
        for (int i = 0; i < 4; i++) {
            int row = i * 32 + wave * 8;
            const unsigned short* gp = A + (size_t)(m0 + row + srow) * GK + k0 + scol;
            unsigned short* lp = lsA + row * BK;   // wave-uniform LDS base
            __builtin_amdgcn_global_load_lds(
                (const __attribute__((address_space(1))) void*)(const void*)gp,
                (__attribute__((address_space(3))) void*)(void*)lp, 16, 0, 0);
        }
        // stage W tile (128 rows x 64 cols bf16)
        for (int i = 0; i < 4; i++) {
            int row = i * 32 + wave * 8;
            const unsigned short* gp = Wq + (size_t)(n0 + row + srow) * GK + k0 + scol;
            unsigned short* lp = lsB + row * BK;
            __builtin_amdgcn_global_load_lds(
                (const __attribute__((address_space(1))) void*)(const void*)gp,
                (__attribute__((address_space(3))) void*)(void*)lp, 16, 0, 0);
        }
        __syncthreads();
        for (int ks = 0; ks < 2; ks++) {
            bf16x8 af[4], bfr[4];
            const short* pa = (const short*)lsA;
            const short* pb = (const short*)lsB;
            for (int i = 0; i < 4; i++)
                af[i] = *(const bf16x8*)(pa + (wm + i * 16 + r) * BK + ks * 32 + quad * 8);
            for (int j = 0; j < 4; j++)
                bfr[j] = *(const bf16x8*)(pb + (wn + j * 16 + r) * BK + ks * 32 + quad * 8);
            for (int i = 0; i < 4; i++)
                for (int j = 0; j < 4; j++)
                    acc[i][j] = __builtin_amdgcn_mfma_f32_16x16x32_bf16(
                        af[i], bfr[j], acc[i][j], 0, 0, 0);
        }
        __syncthreads();
    }

    // Epilogue: per-block uniform half selection (BN=128 divides D_OUT)
    float s_re = sums[0] * (1.0f / (2048.0f * 2048.0f));
    float s_im = sums[1] * (1.0f / (2048.0f * 2048.0f));
    float scale;
    float* obase;
    int ncol0;
    if (n0 < D_OUT) { scale = s_re; obase = out;                        ncol0 = n0; }
    else            { scale = s_im; obase = out + (size_t)GM * D_OUT;   ncol0 = n0 - D_OUT; }

    for (int i = 0; i < 4; i++)
        for (int j = 0; j < 4; j++) {
            int mrow = m0 + wm + i * 16 + quad * 4;   // C/D layout: row=(lane>>4)*4+reg
            int ncol = ncol0 + wn + j * 16 + r;       // col = lane&15
            for (int reg = 0; reg < 4; reg++)
                obase[(size_t)(mrow + reg) * D_OUT + ncol] = acc[i][j][reg] * scale;
        }
}

extern "C" void kernel_launch(void* const* d_in, const int* in_sizes, int n_in,
                              void* d_out, int out_size, void* d_ws, size_t ws_size,
                              hipStream_t stream) {
    const float* xr    = (const float*)d_in[0];
    const float* xi    = (const float*)d_in[1];
    const float* wre   = (const float*)d_in[2];
    const float* wim   = (const float*)d_in[3];
    const float* gamma = (const float*)d_in[4];
    const float* beta  = (const float*)d_in[5];
    float* out = (float*)d_out;

    // ws layout: A bf16 (GM*GK), W_cat bf16 (GN*GK), 2 floats (abs-sums)
    unsigned short* A  = (unsigned short*)d_ws;
    unsigned short* Wq = (unsigned short*)((char*)d_ws + (size_t)GM * GK * 2);
    float* sums = (float*)((char*)d_ws + (size_t)GM * GK * 2 + (size_t)GN * GK * 2);

    hipMemsetAsync(sums, 0, 2 * sizeof(float), stream);
    quant_kernel<<<(D_OUT * D_IN) / 256, 256, 0, stream>>>(wre, wim, Wq, sums);
    ln_kernel<<<GM, 256, 0, stream>>>(xr, xi, gamma, beta, A);
    gemm_kernel<<<dim3(GN / 128, GM / 128), 256, 0, stream>>>(A, Wq, sums, out);
}

// Round 2
// 552.631 us; speedup vs baseline: 1.7338x; 1.7338x over previous
//
#include <hip/hip_runtime.h>
#include <hip/hip_bf16.h>

// Problem constants (from setup_inputs): B=4, S=2048, D_IN=2048, D_OUT=2048
constexpr int D_IN  = 2048;
constexpr int D_OUT = 2048;
constexpr int GM = 4 * 2048;      // B*S rows
constexpr int GK = 2 * D_IN;      // 4096 (concat real|imag)
constexpr int GN = 2 * D_OUT;     // 4096 (concat y_real|y_imag channels)

typedef __attribute__((ext_vector_type(8))) short bf16x8;
typedef __attribute__((ext_vector_type(8))) unsigned short u16x8;
typedef __attribute__((ext_vector_type(4))) float f32x4;

constexpr int QB = 1024;          // quant kernel blocks

// Exact bf16 bit patterns for {0, +-0.5, +-1}; negate = XOR 0x8000.
__device__ inline unsigned short q4bits(float w) {
    if (w >  0.75f) return 0x3F80;   // 1.0
    if (w >  0.25f) return 0x3F00;   // 0.5
    if (w < -0.75f) return 0xBF80;   // -1.0
    if (w < -0.25f) return 0xBF00;   // -0.5
    return 0;
}

__device__ inline unsigned short bf16b(float x) {
    __hip_bfloat16 h = __float2bfloat16(x);
    unsigned short u;
    __builtin_memcpy(&u, &h, 2);
    return u;
}

// ---------------------------------------------------------------------------
// Kernel 1: quantize weights into W_cat (bf16, GN x GK, row-major); per-block
// partial sums of |w_re|, |w_im| -> partial[0..QB-1], partial[QB..2QB-1].
// W_cat row n<2048:  [ qre[n,:] | -qim[n,:] ]   -> y_real channels
// W_cat row n>=2048: [ qim[n,:] |  qre[n,:] ]   -> y_imag channels
// NO same-address atomics (previous version: 32768 serialized atomicAdds
// to 2 addresses = 420us kernel at 1.5% HBM).
// ---------------------------------------------------------------------------
__global__ __launch_bounds__(256) void quant_kernel(
        const float* __restrict__ wre, const float* __restrict__ wim,
        unsigned short* __restrict__ wq, float* __restrict__ partial) {
    float a = 0.f, b = 0.f;
    int tid = blockIdx.x * 256 + threadIdx.x;     // 0 .. 262143
    for (int it = 0; it < 2; it++) {
        int v8 = tid + it * (QB * 256);           // 8-float group, 0 .. 524287
        int idx = v8 * 8;
        int o = idx >> 11;                        // row in D_OUT
        int k = idx & (D_IN - 1);                 // col in D_IN (multiple of 8)
        const float4* pr = (const float4*)(wre + idx);
        const float4* pi = (const float4*)(wim + idx);
        float4 r0 = pr[0], r1 = pr[1];
        float4 i0 = pi[0], i1 = pi[1];
        a += fabsf(r0.x) + fabsf(r0.y) + fabsf(r0.z) + fabsf(r0.w)
           + fabsf(r1.x) + fabsf(r1.y) + fabsf(r1.z) + fabsf(r1.w);
        b += fabsf(i0.x) + fabsf(i0.y) + fabsf(i0.z) + fabsf(i0.w)
           + fabsf(i1.x) + fabsf(i1.y) + fabsf(i1.z) + fabsf(i1.w);
        u16x8 qre, qim, nim;
        qre[0]=q4bits(r0.x); qre[1]=q4bits(r0.y); qre[2]=q4bits(r0.z); qre[3]=q4bits(r0.w);
        qre[4]=q4bits(r1.x); qre[5]=q4bits(r1.y); qre[6]=q4bits(r1.z); qre[7]=q4bits(r1.w);
        qim[0]=q4bits(i0.x); qim[1]=q4bits(i0.y); qim[2]=q4bits(i0.z); qim[3]=q4bits(i0.w);
        qim[4]=q4bits(i1.x); qim[5]=q4bits(i1.y); qim[6]=q4bits(i1.z); qim[7]=q4bits(i1.w);
        for (int j = 0; j < 8; j++) nim[j] = qim[j] ^ 0x8000;
        *(u16x8*)(wq + (size_t)o * GK + k)                  = qre;
        *(u16x8*)(wq + (size_t)o * GK + D_IN + k)           = nim;
        *(u16x8*)(wq + (size_t)(D_OUT + o) * GK + k)        = qim;
        *(u16x8*)(wq + (size_t)(D_OUT + o) * GK + D_IN + k) = qre;
    }
    for (int off = 32; off; off >>= 1) {
        a += __shfl_down(a, off, 64);
        b += __shfl_down(b, off, 64);
    }
    __shared__ float sa[4], sb[4];
    int lane = threadIdx.x & 63, wv = threadIdx.x >> 6;
    if (lane == 0) { sa[wv] = a; sb[wv] = b; }
    __syncthreads();
    if (threadIdx.x == 0) {
        partial[blockIdx.x]      = sa[0] + sa[1] + sa[2] + sa[3];
        partial[QB + blockIdx.x] = sb[0] + sb[1] + sb[2] + sb[3];
    }
}

// Tiny final reduce: partial[2*QB] -> sums[2]
__global__ __launch_bounds__(256) void reduce_kernel(
        const float* __restrict__ partial, float* __restrict__ sums) {
    int t = threadIdx.x;
    float a = 0.f, b = 0.f;
    for (int i = t; i < QB; i += 256) { a += partial[i]; b += partial[QB + i]; }
    for (int off = 32; off; off >>= 1) {
        a += __shfl_down(a, off, 64);
        b += __shfl_down(b, off, 64);
    }
    __shared__ float sa[4], sb[4];
    int lane = t & 63, wv = t >> 6;
    if (lane == 0) { sa[wv] = a; sb[wv] = b; }
    __syncthreads();
    if (t == 0) {
        sums[0] = sa[0] + sa[1] + sa[2] + sa[3];
        sums[1] = sb[0] + sb[1] + sb[2] + sb[3];
    }
}

// ---------------------------------------------------------------------------
// Kernel 2: LayerNorm over concat row [x_real[m,:], x_imag[m,:]] (4096 elems),
// writes bf16 activations A (GM x GK row-major). One 256-thread block per row.
// ---------------------------------------------------------------------------
__global__ __launch_bounds__(256) void ln_kernel(
        const float* __restrict__ xr, const float* __restrict__ xi,
        const float* __restrict__ gamma, const float* __restrict__ beta,
        unsigned short* __restrict__ A) {
    int m = blockIdx.x;
    int t = threadIdx.x;
    const float4* r4 = (const float4*)(xr + (size_t)m * D_IN);
    const float4* i4 = (const float4*)(xi + (size_t)m * D_IN);
    float4 vr[2], vi[2];
    float s = 0.f, ss = 0.f;
    for (int c = 0; c < 2; c++) {
        float4 v = r4[t + c * 256];
        vr[c] = v;
        s  += v.x + v.y + v.z + v.w;
        ss += v.x * v.x + v.y * v.y + v.z * v.z + v.w * v.w;
        v = i4[t + c * 256];
        vi[c] = v;
        s  += v.x + v.y + v.z + v.w;
        ss += v.x * v.x + v.y * v.y + v.z * v.z + v.w * v.w;
    }
    for (int off = 32; off; off >>= 1) {
        s  += __shfl_down(s, off, 64);
        ss += __shfl_down(ss, off, 64);
    }
    __shared__ float red[8];
    __shared__ float smu, srs;
    int lane = t & 63, wv = t >> 6;
    if (lane == 0) { red[wv] = s; red[4 + wv] = ss; }
    __syncthreads();
    if (t == 0) {
        float S  = red[0] + red[1] + red[2] + red[3];
        float SS = red[4] + red[5] + red[6] + red[7];
        float mu  = S * (1.0f / 4096.0f);
        float var = SS * (1.0f / 4096.0f) - mu * mu;
        smu = mu;
        srs = rsqrtf(var + 1e-6f);
    }
    __syncthreads();
    float mu = smu, rs = srs;
    const float4* g4 = (const float4*)gamma;
    const float4* b4 = (const float4*)beta;
    ushort4* Arow = (ushort4*)(A + (size_t)m * GK);
    for (int c = 0; c < 2; c++) {
        int k4 = t + c * 256;                 // float4 index in real half
        float4 g = g4[k4], b = b4[k4];
        float4 v = vr[c];
        ushort4 o;
        o.x = bf16b((v.x - mu) * rs * g.x + b.x);
        o.y = bf16b((v.y - mu) * rs * g.y + b.y);
        o.z = bf16b((v.z - mu) * rs * g.z + b.z);
        o.w = bf16b((v.w - mu) * rs * g.w + b.w);
        Arow[k4] = o;
        g = g4[512 + k4]; b = b4[512 + k4];
        v = vi[c];
        o.x = bf16b((v.x - mu) * rs * g.x + b.x);
        o.y = bf16b((v.y - mu) * rs * g.y + b.y);
        o.z = bf16b((v.z - mu) * rs * g.z + b.z);
        o.w = bf16b((v.w - mu) * rs * g.w + b.w);
        Arow[512 + k4] = o;
    }
}

// ---------------------------------------------------------------------------
// Kernel 3: GEMM  Y(GM x GN) = A(GM x GK) * W_cat^T, W_cat stored N x K.
// 128x128 tile, BK=64, bf16 16x16x32 MFMA, global_load_lds width-16 staging.
// Epilogue scales by s_re / s_im and writes the y_real / y_imag halves.
// ---------------------------------------------------------------------------
__global__ __launch_bounds__(256, 2) void gemm_kernel(
        const unsigned short* __restrict__ A,
        const unsigned short* __restrict__ Wq,
        const float* __restrict__ sums,
        float* __restrict__ out) {
    constexpr int BM = 128, BN = 128, BK = 64;
    __shared__ unsigned short lsA[BM * BK];
    __shared__ unsigned short lsB[BN * BK];
    int n0 = blockIdx.x * BN;
    int m0 = blockIdx.y * BM;
    int t = threadIdx.x, lane = t & 63, wave = t >> 6;
    int wm = (wave >> 1) * 64;     // wave's m offset within tile
    int wn = (wave & 1) * 64;      // wave's n offset within tile
    int quad = lane >> 4, r = lane & 15;
    int srow = lane >> 3;          // staging: row within 8-row group
    int scol = (lane & 7) * 8;     // staging: bf16 col (8 bf16 = 16B)

    f32x4 acc[4][4] = {};

    for (int k0 = 0; k0 < GK; k0 += BK) {
        // stage A tile (128 rows x 64 cols bf16): 4 issues of 16B per thread
        for (int i = 0; i < 4; i++) {
            int row = i * 32 + wave * 8;
            const unsigned short* gp = A + (size_t)(m0 + row + srow) * GK + k0 + scol;
            unsigned short* lp = lsA + row * BK;   // wave-uniform LDS base
            __builtin_amdgcn_global_load_lds(
                (const __attribute__((address_space(1))) void*)(const void*)gp,
                (__attribute__((address_space(3))) void*)(void*)lp, 16, 0, 0);
        }
        // stage W tile (128 rows x 64 cols bf16)
        for (int i = 0; i < 4; i++) {
            int row = i * 32 + wave * 8;
            const unsigned short* gp = Wq + (size_t)(n0 + row + srow) * GK + k0 + scol;
            unsigned short* lp = lsB + row * BK;
            __builtin_amdgcn_global_load_lds(
                (const __attribute__((address_space(1))) void*)(const void*)gp,
                (__attribute__((address_space(3))) void*)(void*)lp, 16, 0, 0);
        }
        __syncthreads();
        for (int ks = 0; ks < 2; ks++) {
            bf16x8 af[4], bfr[4];
            const short* pa = (const short*)lsA;
            const short* pb = (const short*)lsB;
            for (int i = 0; i < 4; i++)
                af[i] = *(const bf16x8*)(pa + (wm + i * 16 + r) * BK + ks * 32 + quad * 8);
            for (int j = 0; j < 4; j++)
                bfr[j] = *(const bf16x8*)(pb + (wn + j * 16 + r) * BK + ks * 32 + quad * 8);
            for (int i = 0; i < 4; i++)
                for (int j = 0; j < 4; j++)
                    acc[i][j] = __builtin_amdgcn_mfma_f32_16x16x32_bf16(
                        af[i], bfr[j], acc[i][j], 0, 0, 0);
        }
        __syncthreads();
    }

    // Epilogue: per-block uniform half selection (BN=128 divides D_OUT)
    float s_re = sums[0] * (1.0f / (2048.0f * 2048.0f));
    float s_im = sums[1] * (1.0f / (2048.0f * 2048.0f));
    float scale;
    float* obase;
    int ncol0;
    if (n0 < D_OUT) { scale = s_re; obase = out;                        ncol0 = n0; }
    else            { scale = s_im; obase = out + (size_t)GM * D_OUT;   ncol0 = n0 - D_OUT; }

    for (int i = 0; i < 4; i++)
        for (int j = 0; j < 4; j++) {
            int mrow = m0 + wm + i * 16 + quad * 4;   // C/D layout: row=(lane>>4)*4+reg
            int ncol = ncol0 + wn + j * 16 + r;       // col = lane&15
            for (int reg = 0; reg < 4; reg++)
                obase[(size_t)(mrow + reg) * D_OUT + ncol] = acc[i][j][reg] * scale;
        }
}

extern "C" void kernel_launch(void* const* d_in, const int* in_sizes, int n_in,
                              void* d_out, int out_size, void* d_ws, size_t ws_size,
                              hipStream_t stream) {
    const float* xr    = (const float*)d_in[0];
    const float* xi    = (const float*)d_in[1];
    const float* wre   = (const float*)d_in[2];
    const float* wim   = (const float*)d_in[3];
    const float* gamma = (const float*)d_in[4];
    const float* beta  = (const float*)d_in[5];
    float* out = (float*)d_out;

    // ws layout: A bf16 (GM*GK), W_cat bf16 (GN*GK), partials (2*QB f32), sums (2 f32)
    unsigned short* A  = (unsigned short*)d_ws;
    unsigned short* Wq = (unsigned short*)((char*)d_ws + (size_t)GM * GK * 2);
    float* partial = (float*)((char*)d_ws + (size_t)GM * GK * 2 + (size_t)GN * GK * 2);
    float* sums = partial + 2 * QB;

    quant_kernel<<<QB, 256, 0, stream>>>(wre, wim, Wq, partial);
    reduce_kernel<<<1, 256, 0, stream>>>(partial, sums);
    ln_kernel<<<GM, 256, 0, stream>>>(xr, xi, gamma, beta, A);
    gemm_kernel<<<dim3(GN / 128, GM / 128), 256, 0, stream>>>(A, Wq, sums, out);
}

// Round 3
// 479.596 us; speedup vs baseline: 1.9978x; 1.1523x over previous
//
#include <hip/hip_runtime.h>
#include <hip/hip_bf16.h>

// Problem constants (from setup_inputs): B=4, S=2048, D_IN=2048, D_OUT=2048
constexpr int D_IN  = 2048;
constexpr int D_OUT = 2048;
constexpr int GM = 4 * 2048;      // B*S rows
constexpr int GK = 2 * D_IN;      // 4096 (concat real|imag)
constexpr int GN = 2 * D_OUT;     // 4096 (concat y_real|y_imag channels)

typedef __attribute__((ext_vector_type(8))) short bf16x8;
typedef __attribute__((ext_vector_type(4))) float f32x4;

constexpr int QB = 1024;          // quant kernel blocks

// Exact bf16 bit patterns for {0, +-0.5, +-1}; negate = XOR 0x8000.
__device__ inline unsigned short q4bits(float w) {
    if (w >  0.75f) return 0x3F80;   // 1.0
    if (w >  0.25f) return 0x3F00;   // 0.5
    if (w < -0.75f) return 0xBF80;   // -1.0
    if (w < -0.25f) return 0xBF00;   // -0.5
    return 0;
}

__device__ inline unsigned short bf16b(float x) {
    __hip_bfloat16 h = __float2bfloat16(x);
    unsigned short u;
    __builtin_memcpy(&u, &h, 2);
    return u;
}

// ---------------------------------------------------------------------------
// Kernel 1: quantize weights into W_cat (bf16, GN x GK, row-major); per-block
// partial sums of |w_re|, |w_im|. Fully coalesced: lane reads one float4 per
// array per step (16B), writes ushort4 (8B).
// W_cat row n<2048:  [ qre[n,:] | -qim[n,:] ]   -> y_real channels
// W_cat row n>=2048: [ qim[n,:] |  qre[n,:] ]   -> y_imag channels
// ---------------------------------------------------------------------------
__global__ __launch_bounds__(256) void quant_kernel(
        const float* __restrict__ wre, const float* __restrict__ wim,
        unsigned short* __restrict__ wq, float* __restrict__ partial) {
    float a = 0.f, b = 0.f;
    int tid = blockIdx.x * 256 + threadIdx.x;     // 0 .. 262143
    const float4* wre4 = (const float4*)wre;
    const float4* wim4 = (const float4*)wim;
    for (int c = 0; c < 4; c++) {
        int f4i = tid + c * (QB * 256);           // float4 index, coalesced
        int idx = f4i * 4;
        int o = idx >> 11;                        // row in D_OUT
        int k = idx & (D_IN - 1);                 // col in D_IN (multiple of 4)
        float4 r = wre4[f4i];
        float4 im = wim4[f4i];
        a += fabsf(r.x) + fabsf(r.y) + fabsf(r.z) + fabsf(r.w);
        b += fabsf(im.x) + fabsf(im.y) + fabsf(im.z) + fabsf(im.w);
        ushort4 qre, qim, nim;
        qre.x = q4bits(r.x);  qre.y = q4bits(r.y);  qre.z = q4bits(r.z);  qre.w = q4bits(r.w);
        qim.x = q4bits(im.x); qim.y = q4bits(im.y); qim.z = q4bits(im.z); qim.w = q4bits(im.w);
        nim.x = qim.x ^ 0x8000; nim.y = qim.y ^ 0x8000;
        nim.z = qim.z ^ 0x8000; nim.w = qim.w ^ 0x8000;
        *(ushort4*)(wq + (size_t)o * GK + k)                  = qre;
        *(ushort4*)(wq + (size_t)o * GK + D_IN + k)           = nim;
        *(ushort4*)(wq + (size_t)(D_OUT + o) * GK + k)        = qim;
        *(ushort4*)(wq + (size_t)(D_OUT + o) * GK + D_IN + k) = qre;
    }
    for (int off = 32; off; off >>= 1) {
        a += __shfl_down(a, off, 64);
        b += __shfl_down(b, off, 64);
    }
    __shared__ float sa[4], sb[4];
    int lane = threadIdx.x & 63, wv = threadIdx.x >> 6;
    if (lane == 0) { sa[wv] = a; sb[wv] = b; }
    __syncthreads();
    if (threadIdx.x == 0) {
        partial[blockIdx.x]      = sa[0] + sa[1] + sa[2] + sa[3];
        partial[QB + blockIdx.x] = sb[0] + sb[1] + sb[2] + sb[3];
    }
}

// Tiny final reduce: partial[2*QB] -> sums[2]
__global__ __launch_bounds__(256) void reduce_kernel(
        const float* __restrict__ partial, float* __restrict__ sums) {
    int t = threadIdx.x;
    float a = 0.f, b = 0.f;
    for (int i = t; i < QB; i += 256) { a += partial[i]; b += partial[QB + i]; }
    for (int off = 32; off; off >>= 1) {
        a += __shfl_down(a, off, 64);
        b += __shfl_down(b, off, 64);
    }
    __shared__ float sa[4], sb[4];
    int lane = t & 63, wv = t >> 6;
    if (lane == 0) { sa[wv] = a; sb[wv] = b; }
    __syncthreads();
    if (t == 0) {
        sums[0] = sa[0] + sa[1] + sa[2] + sa[3];
        sums[1] = sb[0] + sb[1] + sb[2] + sb[3];
    }
}

// ---------------------------------------------------------------------------
// Kernel 2: LayerNorm over concat row [x_real[m,:], x_imag[m,:]] (4096 elems),
// writes bf16 activations A (GM x GK row-major). One 256-thread block per row.
// ---------------------------------------------------------------------------
__global__ __launch_bounds__(256) void ln_kernel(
        const float* __restrict__ xr, const float* __restrict__ xi,
        const float* __restrict__ gamma, const float* __restrict__ beta,
        unsigned short* __restrict__ A) {
    int m = blockIdx.x;
    int t = threadIdx.x;
    const float4* r4 = (const float4*)(xr + (size_t)m * D_IN);
    const float4* i4 = (const float4*)(xi + (size_t)m * D_IN);
    float4 vr[2], vi[2];
    float s = 0.f, ss = 0.f;
    for (int c = 0; c < 2; c++) {
        float4 v = r4[t + c * 256];
        vr[c] = v;
        s  += v.x + v.y + v.z + v.w;
        ss += v.x * v.x + v.y * v.y + v.z * v.z + v.w * v.w;
        v = i4[t + c * 256];
        vi[c] = v;
        s  += v.x + v.y + v.z + v.w;
        ss += v.x * v.x + v.y * v.y + v.z * v.z + v.w * v.w;
    }
    for (int off = 32; off; off >>= 1) {
        s  += __shfl_down(s, off, 64);
        ss += __shfl_down(ss, off, 64);
    }
    __shared__ float red[8];
    __shared__ float smu, srs;
    int lane = t & 63, wv = t >> 6;
    if (lane == 0) { red[wv] = s; red[4 + wv] = ss; }
    __syncthreads();
    if (t == 0) {
        float S  = red[0] + red[1] + red[2] + red[3];
        float SS = red[4] + red[5] + red[6] + red[7];
        float mu  = S * (1.0f / 4096.0f);
        float var = SS * (1.0f / 4096.0f) - mu * mu;
        smu = mu;
        srs = rsqrtf(var + 1e-6f);
    }
    __syncthreads();
    float mu = smu, rs = srs;
    const float4* g4 = (const float4*)gamma;
    const float4* b4 = (const float4*)beta;
    ushort4* Arow = (ushort4*)(A + (size_t)m * GK);
    for (int c = 0; c < 2; c++) {
        int k4 = t + c * 256;                 // float4 index in real half
        float4 g = g4[k4], b = b4[k4];
        float4 v = vr[c];
        ushort4 o;
        o.x = bf16b((v.x - mu) * rs * g.x + b.x);
        o.y = bf16b((v.y - mu) * rs * g.y + b.y);
        o.z = bf16b((v.z - mu) * rs * g.z + b.z);
        o.w = bf16b((v.w - mu) * rs * g.w + b.w);
        Arow[k4] = o;
        g = g4[512 + k4]; b = b4[512 + k4];
        v = vi[c];
        o.x = bf16b((v.x - mu) * rs * g.x + b.x);
        o.y = bf16b((v.y - mu) * rs * g.y + b.y);
        o.z = bf16b((v.z - mu) * rs * g.z + b.z);
        o.w = bf16b((v.w - mu) * rs * g.w + b.w);
        Arow[512 + k4] = o;
    }
}

// ---------------------------------------------------------------------------
// Kernel 3: GEMM  Y(GM x GN) = A(GM x GK) * W_cat^T, W_cat stored N x K.
// 128x128 tile, BK=64, bf16 16x16x32 MFMA, global_load_lds width-16 staging.
// LDS layout is XOR-swizzled: physical 16B-chunk p of row rr holds logical
// chunk p ^ (rr & 7). This makes each group of 8 consecutive reader lanes
// (same quad, r=0..7) cover all 8 chunk positions -> all 32 banks ->
// conflict-free (was 8-way conflict = 1.0e8 SQ_LDS_BANK_CONFLICT cycles).
// Staging lanes fetch global chunk (lane&7)^(lane>>3) so the hardware's
// lane-contiguous LDS placement realizes exactly this swizzle; still within
// one 128B cacheline -> global coalescing unchanged.
// ---------------------------------------------------------------------------
__global__ __launch_bounds__(256, 2) void gemm_kernel(
        const unsigned short* __restrict__ A,
        const unsigned short* __restrict__ Wq,
        const float* __restrict__ sums,
        float* __restrict__ out) {
    constexpr int BM = 128, BN = 128, BK = 64;
    __shared__ unsigned short lsA[BM * BK];
    __shared__ unsigned short lsB[BN * BK];
    int n0 = blockIdx.x * BN;
    int m0 = blockIdx.y * BM;
    int t = threadIdx.x, lane = t & 63, wave = t >> 6;
    int wm = (wave >> 1) * 64;     // wave's m offset within tile
    int wn = (wave & 1) * 64;      // wave's n offset within tile
    int quad = lane >> 4, r = lane & 15;
    int srow = lane >> 3;                     // staging: row within 8-row group
    int scol = ((lane & 7) ^ srow) * 8;       // staging: swizzled bf16 col

    // Reader swizzle: logical chunk (ks*4+quad) of row rr lives at physical
    // chunk ((ks*4+quad) ^ (rr&7)); rr&7 == r&7 for all fragment rows.
    // (x^4)*8 == (x*8)^32, so ks toggles via XOR 32 elements.
    int csw0 = ((quad ^ (r & 7)) * 8);        // element offset, ks=0

    f32x4 acc[4][4] = {};

    for (int k0 = 0; k0 < GK; k0 += BK) {
        // stage A tile (128 rows x 64 cols bf16): 4 issues of 16B per thread
        for (int i = 0; i < 4; i++) {
            int row = i * 32 + wave * 8;
            const unsigned short* gp = A + (size_t)(m0 + row + srow) * GK + k0 + scol;
            unsigned short* lp = lsA + row * BK;   // wave-uniform LDS base
            __builtin_amdgcn_global_load_lds(
                (const __attribute__((address_space(1))) void*)(const void*)gp,
                (__attribute__((address_space(3))) void*)(void*)lp, 16, 0, 0);
        }
        // stage W tile (128 rows x 64 cols bf16)
        for (int i = 0; i < 4; i++) {
            int row = i * 32 + wave * 8;
            const unsigned short* gp = Wq + (size_t)(n0 + row + srow) * GK + k0 + scol;
            unsigned short* lp = lsB + row * BK;
            __builtin_amdgcn_global_load_lds(
                (const __attribute__((address_space(1))) void*)(const void*)gp,
                (__attribute__((address_space(3))) void*)(void*)lp, 16, 0, 0);
        }
        __syncthreads();
        for (int ks = 0; ks < 2; ks++) {
            bf16x8 af[4], bfr[4];
            const short* pa = (const short*)lsA;
            const short* pb = (const short*)lsB;
            int coff = csw0 ^ (ks * 32);
            for (int i = 0; i < 4; i++)
                af[i] = *(const bf16x8*)(pa + (wm + i * 16 + r) * BK + coff);
            for (int j = 0; j < 4; j++)
                bfr[j] = *(const bf16x8*)(pb + (wn + j * 16 + r) * BK + coff);
            for (int i = 0; i < 4; i++)
                for (int j = 0; j < 4; j++)
                    acc[i][j] = __builtin_amdgcn_mfma_f32_16x16x32_bf16(
                        af[i], bfr[j], acc[i][j], 0, 0, 0);
        }
        __syncthreads();
    }

    // Epilogue: per-block uniform half selection (BN=128 divides D_OUT)
    float s_re = sums[0] * (1.0f / (2048.0f * 2048.0f));
    float s_im = sums[1] * (1.0f / (2048.0f * 2048.0f));
    float scale;
    float* obase;
    int ncol0;
    if (n0 < D_OUT) { scale = s_re; obase = out;                        ncol0 = n0; }
    else            { scale = s_im; obase = out + (size_t)GM * D_OUT;   ncol0 = n0 - D_OUT; }

    for (int i = 0; i < 4; i++)
        for (int j = 0; j < 4; j++) {
            int mrow = m0 + wm + i * 16 + quad * 4;   // C/D layout: row=(lane>>4)*4+reg
            int ncol = ncol0 + wn + j * 16 + r;       // col = lane&15
            for (int reg = 0; reg < 4; reg++)
                obase[(size_t)(mrow + reg) * D_OUT + ncol] = acc[i][j][reg] * scale;
        }
}

extern "C" void kernel_launch(void* const* d_in, const int* in_sizes, int n_in,
                              void* d_out, int out_size, void* d_ws, size_t ws_size,
                              hipStream_t stream) {
    const float* xr    = (const float*)d_in[0];
    const float* xi    = (const float*)d_in[1];
    const float* wre   = (const float*)d_in[2];
    const float* wim   = (const float*)d_in[3];
    const float* gamma = (const float*)d_in[4];
    const float* beta  = (const float*)d_in[5];
    float* out = (float*)d_out;

    // ws layout: A bf16 (GM*GK), W_cat bf16 (GN*GK), partials (2*QB f32), sums (2 f32)
    unsigned short* A  = (unsigned short*)d_ws;
    unsigned short* Wq = (unsigned short*)((char*)d_ws + (size_t)GM * GK * 2);
    float* partial = (float*)((char*)d_ws + (size_t)GM * GK * 2 + (size_t)GN * GK * 2);
    float* sums = partial + 2 * QB;

    quant_kernel<<<QB, 256, 0, stream>>>(wre, wim, Wq, partial);
    reduce_kernel<<<1, 256, 0, stream>>>(partial, sums);
    ln_kernel<<<GM, 256, 0, stream>>>(xr, xi, gamma, beta, A);
    gemm_kernel<<<dim3(GN / 128, GM / 128), 256, 0, stream>>>(A, Wq, sums, out);
}